// Round 8
// baseline (36.836 us; speedup 1.0000x reference)
//
#include <hip/hip_runtime.h>
#include <hip/hip_bf16.h>

typedef __attribute__((ext_vector_type(4))) float f32x4;
typedef __attribute__((ext_vector_type(8))) __bf16 bf16x8;
typedef __attribute__((ext_vector_type(4))) __bf16 bf16x4;

#define B_DIM 16
#define L_DIM 1024
#define D_DIM 256

#define GLOAD_LDS16(g, lptr)                                          \
    __builtin_amdgcn_global_load_lds(                                 \
        (const __attribute__((address_space(1))) void*)(g),           \
        (__attribute__((address_space(3))) void*)(lptr), 16, 0, 0)

// ---------------------------------------------------------------------------
// Prep: row norms + fp32->bf16 conversion in one pass (r4-proven version).
// ---------------------------------------------------------------------------
__global__ __launch_bounds__(256) void prep_kernel(const float* __restrict__ s1,
                                                   const float* __restrict__ s2,
                                                   float* __restrict__ nrm,
                                                   __hip_bfloat16* __restrict__ s1b,
                                                   __hip_bfloat16* __restrict__ s2b) {
    const int w = threadIdx.x >> 6, l = threadIdx.x & 63;
    const int base = (blockIdx.x << 4) + (w << 2);  // 16 rows/block, 4/wave
#pragma unroll
    for (int i = 0; i < 4; ++i) {
        const int row = base + i;          // 0 .. 32767
        const int second = row >> 14;      // rows >= 16384 are s2 (wave-uniform)
        const int r = row & 16383;
        const float* src = (second ? s2 : s1) + (size_t)r * D_DIM;
        __hip_bfloat16* dst = (second ? s2b : s1b) + (size_t)r * D_DIM;
        float4 v = reinterpret_cast<const float4*>(src)[l];
        float s = v.x * v.x + v.y * v.y + v.z * v.z + v.w * v.w;
        bf16x4 bv;
        bv[0] = (__bf16)v.x; bv[1] = (__bf16)v.y; bv[2] = (__bf16)v.z; bv[3] = (__bf16)v.w;
        *reinterpret_cast<bf16x4*>(dst + l * 4) = bv;
#pragma unroll
        for (int o = 32; o > 0; o >>= 1) s += __shfl_xor(s, o, 64);
        if (l == 0) nrm[row] = s;
    }
}

// ---------------------------------------------------------------------------
// Main GEMM: 128x64 tile (BMxBN), BK=32, 4 waves, grid 2048 -> 48 KB LDS
// -> 3 blocks/CU (phase mixing: some blocks store while others compute).
// r4-proven pipeline: 4 LDS buffers, stage(kt+3) at step kt, counted vmcnt(3)
// (3 gload_lds per stage), one barrier/step, frags read one step ahead with
// lgkmcnt(6) (6 ds_read per frag set).
// Overwrite safety: stage(kt+3) -> buf[(kt+3)&3]=buf[(kt-1)&3]; frags(kt-1)
// reads drained by lgkm@kt-1 before barrier@kt orders them globally.
// ---------------------------------------------------------------------------
__global__ __launch_bounds__(256) void dist_gemm_bf16_kernel(const __hip_bfloat16* __restrict__ s1b,
                                                             const __hip_bfloat16* __restrict__ s2b,
                                                             const float* __restrict__ nrm,
                                                             float* __restrict__ out) {
    __shared__ __bf16 Alds[4][128 * 32];   // 32 KB
    __shared__ __bf16 Blds[4][64 * 32];    // 16 KB

    const int t = threadIdx.x;
    const int p = blockIdx.x;
    // XCD-aware swizzle: XCD x owns logical tiles [256x, 256x+256) = batches 2x,2x+1.
    const int d = ((p & 7) << 8) + (p >> 3);  // bijective for 2048 blocks
    const int batch = d >> 7;
    const int tile = d & 127;                 // 8 row-tiles x 16 col-tiles
    const int row0 = (tile >> 4) << 7;        // 128-row tile
    const int col0 = (tile & 15) << 6;        // 64-col tile

    const __hip_bfloat16* Ag = s1b + ((size_t)batch * L_DIM + row0) * D_DIM;
    const __hip_bfloat16* Bg = s2b + ((size_t)batch * L_DIM + col0) * D_DIM;

    const int l = t & 63, w = t >> 6;
    const int wr = w >> 1, wc = w & 1;   // wave -> 64x32 output quadrant
    const int lr = l & 15;               // frag row (A) / col (B,C)
    const int lq = l >> 4;               // quarter = base 16B slot

    // staging: 12 segs of 16 rows (A: segs 0-7, B: segs 8-11); wave w owns
    // segs 3w..3w+2. lane l -> row-in-seg l>>2, linear slot l&3; global
    // SOURCE slot pre-swizzled (l&3)^((row>>1)&3) = (l&3)^((l>>3)&3).
    const int srow_in_seg = l >> 2;
    const int sslot = (l & 3) ^ ((l >> 3) & 3);

    f32x4 acc[4][2] = {};

    auto stageK = [&](int kt) {          // 3 gload_lds per wave, buf kt&3
        const int k0 = kt << 5;
        const int b = kt & 3;
#pragma unroll
        for (int i = 0; i < 3; ++i) {
            const int s = w * 3 + i;
            if (s < 8) {
                const int rl = (s << 4) + srow_in_seg;
                GLOAD_LDS16(Ag + rl * D_DIM + k0 + sslot * 8, &Alds[b][s << 9]);
            } else {
                const int rl = ((s - 8) << 4) + srow_in_seg;
                GLOAD_LDS16(Bg + rl * D_DIM + k0 + sslot * 8, &Blds[b][(s - 8) << 9]);
            }
        }
    };

    auto readFrags = [&](int kt, bf16x8* aF, bf16x8* bF) {  // 6 ds_read_b128
        const int b = kt & 3;
#pragma unroll
        for (int m = 0; m < 4; ++m) {
            const int row = (wr << 6) + (m << 4) + lr;
            const int sl = lq ^ ((row >> 1) & 3);
            aF[m] = *reinterpret_cast<const bf16x8*>(&Alds[b][(row << 5) + (sl << 3)]);
        }
#pragma unroll
        for (int n = 0; n < 2; ++n) {
            const int row = (wc << 5) + (n << 4) + lr;
            const int sl = lq ^ ((row >> 1) & 3);
            bF[n] = *reinterpret_cast<const bf16x8*>(&Blds[b][(row << 5) + (sl << 3)]);
        }
    };

    bf16x8 aF[2][4], bF[2][2];

    // Prologue: 3 stages in flight (9 loads); drain stage0+stage1 (keep stage2's 3).
    stageK(0); stageK(1); stageK(2);
    asm volatile("s_waitcnt vmcnt(3)" ::: "memory");
    __builtin_amdgcn_s_barrier();
    readFrags(0, aF[0], bF[0]);

#pragma unroll
    for (int kt = 0; kt < 8; ++kt) {
        if (kt >= 1) {
            // pending: stage(kt+1) [oldest, 3 loads] + stage(kt+2) [3 loads]
            if (kt <= 5) asm volatile("s_waitcnt vmcnt(3)" ::: "memory");
            else         asm volatile("s_waitcnt vmcnt(0)" ::: "memory");
            __builtin_amdgcn_s_barrier();
        }
        if (kt < 7) readFrags(kt + 1, aF[(kt + 1) & 1], bF[(kt + 1) & 1]);
        // drain frags(kt) (oldest 6 lgkm ops), keep frags(kt+1) in flight
        if (kt < 7) asm volatile("s_waitcnt lgkmcnt(6)" ::: "memory");
        else        asm volatile("s_waitcnt lgkmcnt(0)" ::: "memory");
        if (kt <= 4) stageK(kt + 3);

        __builtin_amdgcn_s_setprio(1);
#pragma unroll
        for (int m = 0; m < 4; ++m)
#pragma unroll
            for (int n = 0; n < 2; ++n)
                acc[m][n] = __builtin_amdgcn_mfma_f32_16x16x32_bf16(
                    aF[kt & 1][m], bF[kt & 1][n], acc[m][n], 0, 0, 0);
        __builtin_amdgcn_s_setprio(0);
    }

    // epilogue
    const float* x2 = nrm + batch * L_DIM;
    const float* y2 = nrm + B_DIM * L_DIM + batch * L_DIM;
    float* outb = out + (size_t)batch * L_DIM * L_DIM;
    const int rbase = row0 + (wr << 6) + (lq << 2);
    const int cbase = col0 + (wc << 5) + lr;
#pragma unroll
    for (int n = 0; n < 2; ++n) {
        const int col = cbase + (n << 4);
        const float y2v = y2[col];
#pragma unroll
        for (int m = 0; m < 4; ++m) {
            const int rowf = rbase + (m << 4);
#pragma unroll
            for (int r = 0; r < 4; ++r) {
                const int row = rowf + r;
                float sq = x2[row] + y2v - 2.0f * acc[m][n][r];
                sq = fmaxf(sq, 0.0f);
                float den = 1.0f + __builtin_amdgcn_sqrtf(sq);
                outb[(size_t)row * L_DIM + col] = __builtin_amdgcn_rcpf(den);
            }
        }
    }
}

// ---------------------------------------------------------------------------
// Fallback path for the case ws_size < needed.
// ---------------------------------------------------------------------------
__global__ __launch_bounds__(256) void norms_kernel(const float* __restrict__ s1,
                                                    const float* __restrict__ s2,
                                                    float* __restrict__ nrm) {
    int w = threadIdx.x >> 6, l = threadIdx.x & 63;
    int row = (blockIdx.x << 2) + w;
    const float* src = (row < B_DIM * L_DIM)
                           ? (s1 + (size_t)row * D_DIM)
                           : (s2 + (size_t)(row - B_DIM * L_DIM) * D_DIM);
    float4 v = reinterpret_cast<const float4*>(src)[l];
    float s = v.x * v.x + v.y * v.y + v.z * v.z + v.w * v.w;
#pragma unroll
    for (int o = 32; o > 0; o >>= 1) s += __shfl_xor(s, o, 64);
    if (l == 0) nrm[row] = s;
}

__global__ __launch_bounds__(256) void dist_gemm_kernel(const float* __restrict__ s1,
                                                        const float* __restrict__ s2,
                                                        const float* __restrict__ nrm,
                                                        float* __restrict__ out) {
    __shared__ __bf16 Alds[2][128 * 32];
    __shared__ __bf16 Blds[2][128 * 32];

    const int t = threadIdx.x;
    const int p = blockIdx.x;
    const int d = ((p & 7) << 7) + (p >> 3);
    const int batch = d >> 6;
    const int tile = d & 63;
    const int row0 = (tile >> 3) << 7;
    const int col0 = (tile & 7) << 7;

    const float* Ag = s1 + ((size_t)batch * L_DIM + row0) * D_DIM;
    const float* Bg = s2 + ((size_t)batch * L_DIM + col0) * D_DIM;

    const int sr = t >> 2;
    const int sc = (t & 3) << 3;

    const int l = t & 63, w = t >> 6;
    const int wr = w >> 1, wc = w & 1;
    const int lr = l & 15;
    const int lk = (l >> 4) << 3;

    f32x4 acc[4][4] = {};

    auto stage = [&](int buf, int k0) {
#pragma unroll
        for (int pass = 0; pass < 2; ++pass) {
            const int r = sr + (pass << 6);
            const float4* sa = reinterpret_cast<const float4*>(Ag + (size_t)r * D_DIM + k0 + sc);
            float4 a0 = sa[0], a1 = sa[1];
            const float4* sb = reinterpret_cast<const float4*>(Bg + (size_t)r * D_DIM + k0 + sc);
            float4 b0 = sb[0], b1 = sb[1];
            bf16x8 av, bv;
            av[0] = (__bf16)a0.x; av[1] = (__bf16)a0.y; av[2] = (__bf16)a0.z; av[3] = (__bf16)a0.w;
            av[4] = (__bf16)a1.x; av[5] = (__bf16)a1.y; av[6] = (__bf16)a1.z; av[7] = (__bf16)a1.w;
            bv[0] = (__bf16)b0.x; bv[1] = (__bf16)b0.y; bv[2] = (__bf16)b0.z; bv[3] = (__bf16)b0.w;
            bv[4] = (__bf16)b1.x; bv[5] = (__bf16)b1.y; bv[6] = (__bf16)b1.z; bv[7] = (__bf16)b1.w;
            *reinterpret_cast<bf16x8*>(&Alds[buf][(r << 5) + sc]) = av;
            *reinterpret_cast<bf16x8*>(&Blds[buf][(r << 5) + sc]) = bv;
        }
    };

    stage(0, 0);
    __syncthreads();
    int cur = 0;
    for (int kt = 0; kt < 8; ++kt) {
        if (kt < 7) stage(cur ^ 1, (kt + 1) << 5);
        bf16x8 aF[4], bF[4];
#pragma unroll
        for (int m = 0; m < 4; ++m)
            aF[m] = *reinterpret_cast<const bf16x8*>(
                &Alds[cur][(((wr << 6) + (m << 4) + lr) << 5) + lk]);
#pragma unroll
        for (int n = 0; n < 4; ++n)
            bF[n] = *reinterpret_cast<const bf16x8*>(
                &Blds[cur][(((wc << 6) + (n << 4) + lr) << 5) + lk]);
#pragma unroll
        for (int m = 0; m < 4; ++m)
#pragma unroll
            for (int n = 0; n < 4; ++n)
                acc[m][n] = __builtin_amdgcn_mfma_f32_16x16x32_bf16(aF[m], bF[n], acc[m][n], 0, 0, 0);
        __syncthreads();
        cur ^= 1;
    }

    const float* x2 = nrm + batch * L_DIM;
    const float* y2 = nrm + B_DIM * L_DIM + batch * L_DIM;
    float* outb = out + (size_t)batch * L_DIM * L_DIM;
    const int rbase = row0 + (wr << 6) + ((l >> 4) << 2);
    const int cbase = col0 + (wc << 6) + lr;
#pragma unroll
    for (int n = 0; n < 4; ++n) {
        const int col = cbase + (n << 4);
        const float y2v = y2[col];
#pragma unroll
        for (int m = 0; m < 4; ++m) {
            const int rowf = rbase + (m << 4);
#pragma unroll
            for (int r = 0; r < 4; ++r) {
                const int row = rowf + r;
                float sq = x2[row] + y2v - 2.0f * acc[m][n][r];
                sq = fmaxf(sq, 0.0f);
                outb[(size_t)row * L_DIM + col] = 1.0f / (1.0f + sqrtf(sq));
            }
        }
    }
}

extern "C" void kernel_launch(void* const* d_in, const int* in_sizes, int n_in,
                              void* d_out, int out_size, void* d_ws, size_t ws_size,
                              hipStream_t stream) {
    (void)in_sizes; (void)n_in; (void)out_size;
    const float* s1 = (const float*)d_in[1];
    const float* s2 = (const float*)d_in[2];
    float* out = (float*)d_out;

    const size_t NRM_BYTES = 2u * B_DIM * L_DIM * sizeof(float);          // 128 KB
    const size_t BF_BYTES = (size_t)B_DIM * L_DIM * D_DIM * sizeof(__hip_bfloat16);  // 8 MB each
    const size_t NEED = NRM_BYTES + 2 * BF_BYTES;                          // ~16.9 MB

    float* nrm = (float*)d_ws;
    if (ws_size >= NEED) {
        __hip_bfloat16* s1b = (__hip_bfloat16*)((char*)d_ws + NRM_BYTES);
        __hip_bfloat16* s2b = (__hip_bfloat16*)((char*)d_ws + NRM_BYTES + BF_BYTES);
        prep_kernel<<<2048, 256, 0, stream>>>(s1, s2, nrm, s1b, s2b);
        dist_gemm_bf16_kernel<<<2048, 256, 0, stream>>>(s1b, s2b, nrm, out);
    } else {
        norms_kernel<<<8192, 256, 0, stream>>>(s1, s2, nrm);
        dist_gemm_kernel<<<1024, 256, 0, stream>>>(s1, s2, nrm, out);
    }
}

// Round 9
// 32.166 us; speedup vs baseline: 1.1452x; 1.1452x over previous
//
#include <hip/hip_runtime.h>
#include <hip/hip_bf16.h>

typedef __attribute__((ext_vector_type(4))) float f32x4;
typedef __attribute__((ext_vector_type(8))) __bf16 bf16x8;
typedef __attribute__((ext_vector_type(4))) __bf16 bf16x4;

#define B_DIM 16
#define L_DIM 1024
#define D_DIM 256

#define GLOAD_LDS16(g, lptr)                                          \
    __builtin_amdgcn_global_load_lds(                                 \
        (const __attribute__((address_space(1))) void*)(g),           \
        (__attribute__((address_space(3))) void*)(lptr), 16, 0, 0)

#define SBAR() __builtin_amdgcn_sched_barrier(0)

// ---------------------------------------------------------------------------
// Prep: row norms + fp32->bf16 conversion in one pass (r4-proven).
// ---------------------------------------------------------------------------
__global__ __launch_bounds__(256) void prep_kernel(const float* __restrict__ s1,
                                                   const float* __restrict__ s2,
                                                   float* __restrict__ nrm,
                                                   __hip_bfloat16* __restrict__ s1b,
                                                   __hip_bfloat16* __restrict__ s2b) {
    const int w = threadIdx.x >> 6, l = threadIdx.x & 63;
    const int base = (blockIdx.x << 4) + (w << 2);  // 16 rows/block, 4/wave
#pragma unroll
    for (int i = 0; i < 4; ++i) {
        const int row = base + i;          // 0 .. 32767
        const int second = row >> 14;      // rows >= 16384 are s2 (wave-uniform)
        const int r = row & 16383;
        const float* src = (second ? s2 : s1) + (size_t)r * D_DIM;
        __hip_bfloat16* dst = (second ? s2b : s1b) + (size_t)r * D_DIM;
        float4 v = reinterpret_cast<const float4*>(src)[l];
        float s = v.x * v.x + v.y * v.y + v.z * v.z + v.w * v.w;
        bf16x4 bv;
        bv[0] = (__bf16)v.x; bv[1] = (__bf16)v.y; bv[2] = (__bf16)v.z; bv[3] = (__bf16)v.w;
        *reinterpret_cast<bf16x4*>(dst + l * 4) = bv;
#pragma unroll
        for (int o = 32; o > 0; o >>= 1) s += __shfl_xor(s, o, 64);
        if (l == 0) nrm[row] = s;
    }
}

// ---------------------------------------------------------------------------
// Persistent 2-tile GEMM. Grid 512, 2 blocks/CU, each block does two
// col-adjacent 128x128 tiles of one row-panel (A reused, xv norms shared).
// Per tile: r4-proven pipeline (4 LDS bufs, stage(kt+3), counted vmcnt,
// one barrier/step, frags 1 ahead, lgkmcnt(8)).
// Tile transition: stage tile1(0..2) -> yv1 loads -> epilogue0 VALU+stores
// (fire-and-forget) -> vmcnt(24) -> barrier. Stores overlap tile1's K-loop.
// vmcnt counts use in-order retirement; sched_barrier(0) pins group order.
// ---------------------------------------------------------------------------
__global__ __launch_bounds__(256, 2) void dist_gemm2_kernel(const __hip_bfloat16* __restrict__ s1b,
                                                            const __hip_bfloat16* __restrict__ s2b,
                                                            const float* __restrict__ nrm,
                                                            float* __restrict__ out) {
    __shared__ __bf16 Alds[4][128 * 32];
    __shared__ __bf16 Blds[4][128 * 32];

    const int t = threadIdx.x;
    const int p = blockIdx.x;
    // XCD swizzle (512 blocks): XCD x owns d in [64x,64x+64) = batches 2x,2x+1.
    const int d = ((p & 7) << 6) + (p >> 3);
    const int batch = d >> 5;
    const int rem = d & 31;                    // 8 row-panels x 4 col-pairs
    const int row0 = (rem >> 2) << 7;
    const int col0a = (rem & 3) << 8;          // u*256
    const int col0b = col0a + 128;

    const __hip_bfloat16* Ag = s1b + ((size_t)batch * L_DIM + row0) * D_DIM;
    const __hip_bfloat16* Bg0 = s2b + ((size_t)batch * L_DIM + col0a) * D_DIM;
    const __hip_bfloat16* Bg1 = s2b + ((size_t)batch * L_DIM + col0b) * D_DIM;

    const int l = t & 63, w = t >> 6;
    const int wr = w >> 1, wc = w & 1;   // wave -> 64x64 quadrant
    const int lr = l & 15;               // frag row (A) / col (B,C)
    const int lq = l >> 4;               // quarter = base 16B slot

    const int srow_in_seg = l >> 2;
    const int sslot = (l & 3) ^ ((l >> 3) & 3);

    auto stageK = [&](const __hip_bfloat16* Bg, int kt) {  // 4 gload_lds
        const int k0 = kt << 5;
        const int b = kt & 3;
#pragma unroll
        for (int i = 0; i < 2; ++i) {
            const int s = (w << 1) | i;
            const int rl = (s << 4) + srow_in_seg;
            GLOAD_LDS16(Ag + rl * D_DIM + k0 + sslot * 8, &Alds[b][s << 9]);
            GLOAD_LDS16(Bg + rl * D_DIM + k0 + sslot * 8, &Blds[b][s << 9]);
        }
    };

    bf16x8 aF[2][4], bF[2][4];
    auto readFrags = [&](int kt, bf16x8* a, bf16x8* bfr) {  // 8 ds_read_b128
        const int b = kt & 3;
#pragma unroll
        for (int m = 0; m < 4; ++m) {
            const int row = (wr << 6) + (m << 4) + lr;
            const int sl = lq ^ ((row >> 1) & 3);
            a[m] = *reinterpret_cast<const bf16x8*>(&Alds[b][(row << 5) + (sl << 3)]);
        }
#pragma unroll
        for (int n = 0; n < 4; ++n) {
            const int row = (wc << 6) + (n << 4) + lr;
            const int sl = lq ^ ((row >> 1) & 3);
            bfr[n] = *reinterpret_cast<const bf16x8*>(&Blds[b][(row << 5) + (sl << 3)]);
        }
    };

    const float* x2 = nrm + batch * L_DIM;
    const float* y2 = nrm + B_DIM * L_DIM + batch * L_DIM;
    const int rbase = row0 + (wr << 6) + (lq << 2);   // 4 consecutive rows per m
    const int cloc = (wc << 6) + lr;                  // col within tile

    float* outb = out + (size_t)batch * L_DIM * L_DIM;
    auto epilogue = [&](const f32x4 (&acc)[4][4], const f32x4 (&xv)[4],
                        const float (&yv)[4], int col0_) {
        const int cb = col0_ + cloc;
#pragma unroll
        for (int n = 0; n < 4; ++n) {
            const int col = cb + (n << 4);
            const float y2v = yv[n];
#pragma unroll
            for (int m = 0; m < 4; ++m) {
#pragma unroll
                for (int r = 0; r < 4; ++r) {
                    const int row = rbase + (m << 4) + r;
                    float sq = xv[m][r] + y2v - 2.0f * acc[m][n][r];
                    sq = fmaxf(sq, 0.0f);
                    float den = 1.0f + __builtin_amdgcn_sqrtf(sq);
                    outb[(size_t)row * L_DIM + col] = __builtin_amdgcn_rcpf(den);
                }
            }
        }
    };

    // ============================ TILE 0 =============================
    f32x4 acc0[4][4] = {};
    // op stream: [1-12] stages 0-2 | [13-20] xv+yv0 | loop adds stage3..7
    stageK(Bg0, 0); stageK(Bg0, 1); stageK(Bg0, 2);
    SBAR();
    f32x4 xv[4]; float yv0[4];
#pragma unroll
    for (int m = 0; m < 4; ++m) xv[m] = *reinterpret_cast<const f32x4*>(&x2[rbase + (m << 4)]);
#pragma unroll
    for (int n = 0; n < 4; ++n) yv0[n] = y2[col0a + cloc + (n << 4)];
    SBAR();
    asm volatile("s_waitcnt vmcnt(12)" ::: "memory");   // stage0,1 landed
    __builtin_amdgcn_s_barrier();
    readFrags(0, aF[0], bF[0]);

#pragma unroll
    for (int kt = 0; kt < 8; ++kt) {
        if (kt == 1)      asm volatile("s_waitcnt vmcnt(12)" ::: "memory");
        else if (kt >= 2 && kt <= 5) asm volatile("s_waitcnt vmcnt(4)" ::: "memory");
        else if (kt >= 6) asm volatile("s_waitcnt vmcnt(0)" ::: "memory");
        if (kt >= 1) __builtin_amdgcn_s_barrier();
        if (kt < 7) readFrags(kt + 1, aF[(kt + 1) & 1], bF[(kt + 1) & 1]);
        if (kt < 7) asm volatile("s_waitcnt lgkmcnt(8)" ::: "memory");
        else        asm volatile("s_waitcnt lgkmcnt(0)" ::: "memory");
        if (kt <= 4) stageK(Bg0, kt + 3);
        __builtin_amdgcn_s_setprio(1);
#pragma unroll
        for (int m = 0; m < 4; ++m)
#pragma unroll
            for (int n = 0; n < 4; ++n)
                acc0[m][n] = __builtin_amdgcn_mfma_f32_16x16x32_bf16(
                    aF[kt & 1][m], bF[kt & 1][n], acc0[m][n], 0, 0, 0);
        __builtin_amdgcn_s_setprio(0);
    }

    // ======================= TRANSITION / TILE 1 =====================
    // op stream (fresh, all prior vmem drained at kt=6's vmcnt(0)):
    // [1-12] stages 0-2 | [13-16] yv1 | [17-32] epilogue0 stores | loop st3..7
    stageK(Bg1, 0); stageK(Bg1, 1); stageK(Bg1, 2);
    SBAR();
    float yv1[4];
#pragma unroll
    for (int n = 0; n < 4; ++n) yv1[n] = y2[col0b + cloc + (n << 4)];
    SBAR();
    epilogue(acc0, xv, yv0, col0a);   // VALU + 16 fire-and-forget stores
    SBAR();
    asm volatile("s_waitcnt vmcnt(24)" ::: "memory");   // stage0,1 landed
    __builtin_amdgcn_s_barrier();

    f32x4 acc1[4][4] = {};
    readFrags(0, aF[0], bF[0]);

#pragma unroll
    for (int kt = 0; kt < 8; ++kt) {
        if (kt == 1)      asm volatile("s_waitcnt vmcnt(24)" ::: "memory");
        else if (kt >= 2 && kt <= 5) asm volatile("s_waitcnt vmcnt(4)" ::: "memory");
        else if (kt >= 6) asm volatile("s_waitcnt vmcnt(0)" ::: "memory");
        if (kt >= 1) __builtin_amdgcn_s_barrier();
        if (kt < 7) readFrags(kt + 1, aF[(kt + 1) & 1], bF[(kt + 1) & 1]);
        if (kt < 7) asm volatile("s_waitcnt lgkmcnt(8)" ::: "memory");
        else        asm volatile("s_waitcnt lgkmcnt(0)" ::: "memory");
        if (kt <= 4) stageK(Bg1, kt + 3);
        __builtin_amdgcn_s_setprio(1);
#pragma unroll
        for (int m = 0; m < 4; ++m)
#pragma unroll
            for (int n = 0; n < 4; ++n)
                acc1[m][n] = __builtin_amdgcn_mfma_f32_16x16x32_bf16(
                    aF[kt & 1][m], bF[kt & 1][n], acc1[m][n], 0, 0, 0);
        __builtin_amdgcn_s_setprio(0);
    }

    epilogue(acc1, xv, yv1, col0b);
}

// ---------------------------------------------------------------------------
// Fallback path for the case ws_size < needed.
// ---------------------------------------------------------------------------
__global__ __launch_bounds__(256) void norms_kernel(const float* __restrict__ s1,
                                                    const float* __restrict__ s2,
                                                    float* __restrict__ nrm) {
    int w = threadIdx.x >> 6, l = threadIdx.x & 63;
    int row = (blockIdx.x << 2) + w;
    const float* src = (row < B_DIM * L_DIM)
                           ? (s1 + (size_t)row * D_DIM)
                           : (s2 + (size_t)(row - B_DIM * L_DIM) * D_DIM);
    float4 v = reinterpret_cast<const float4*>(src)[l];
    float s = v.x * v.x + v.y * v.y + v.z * v.z + v.w * v.w;
#pragma unroll
    for (int o = 32; o > 0; o >>= 1) s += __shfl_xor(s, o, 64);
    if (l == 0) nrm[row] = s;
}

__global__ __launch_bounds__(256) void dist_gemm_kernel(const float* __restrict__ s1,
                                                        const float* __restrict__ s2,
                                                        const float* __restrict__ nrm,
                                                        float* __restrict__ out) {
    __shared__ __bf16 Alds[2][128 * 32];
    __shared__ __bf16 Blds[2][128 * 32];

    const int t = threadIdx.x;
    const int p = blockIdx.x;
    const int d = ((p & 7) << 7) + (p >> 3);
    const int batch = d >> 6;
    const int tile = d & 63;
    const int row0 = (tile >> 3) << 7;
    const int col0 = (tile & 7) << 7;

    const float* Ag = s1 + ((size_t)batch * L_DIM + row0) * D_DIM;
    const float* Bg = s2 + ((size_t)batch * L_DIM + col0) * D_DIM;

    const int sr = t >> 2;
    const int sc = (t & 3) << 3;

    const int l = t & 63, w = t >> 6;
    const int wr = w >> 1, wc = w & 1;
    const int lr = l & 15;
    const int lk = (l >> 4) << 3;

    f32x4 acc[4][4] = {};

    auto stage = [&](int buf, int k0) {
#pragma unroll
        for (int pass = 0; pass < 2; ++pass) {
            const int r = sr + (pass << 6);
            const float4* sa = reinterpret_cast<const float4*>(Ag + (size_t)r * D_DIM + k0 + sc);
            float4 a0 = sa[0], a1 = sa[1];
            const float4* sb = reinterpret_cast<const float4*>(Bg + (size_t)r * D_DIM + k0 + sc);
            float4 b0 = sb[0], b1 = sb[1];
            bf16x8 av, bv;
            av[0] = (__bf16)a0.x; av[1] = (__bf16)a0.y; av[2] = (__bf16)a0.z; av[3] = (__bf16)a0.w;
            av[4] = (__bf16)a1.x; av[5] = (__bf16)a1.y; av[6] = (__bf16)a1.z; av[7] = (__bf16)a1.w;
            bv[0] = (__bf16)b0.x; bv[1] = (__bf16)b0.y; bv[2] = (__bf16)b0.z; bv[3] = (__bf16)b0.w;
            bv[4] = (__bf16)b1.x; bv[5] = (__bf16)b1.y; bv[6] = (__bf16)b1.z; bv[7] = (__bf16)b1.w;
            *reinterpret_cast<bf16x8*>(&Alds[buf][(r << 5) + sc]) = av;
            *reinterpret_cast<bf16x8*>(&Blds[buf][(r << 5) + sc]) = bv;
        }
    };

    stage(0, 0);
    __syncthreads();
    int cur = 0;
    for (int kt = 0; kt < 8; ++kt) {
        if (kt < 7) stage(cur ^ 1, (kt + 1) << 5);
        bf16x8 aF[4], bF[4];
#pragma unroll
        for (int m = 0; m < 4; ++m)
            aF[m] = *reinterpret_cast<const bf16x8*>(
                &Alds[cur][(((wr << 6) + (m << 4) + lr) << 5) + lk]);
#pragma unroll
        for (int n = 0; n < 4; ++n)
            bF[n] = *reinterpret_cast<const bf16x8*>(
                &Blds[cur][(((wc << 6) + (n << 4) + lr) << 5) + lk]);
#pragma unroll
        for (int m = 0; m < 4; ++m)
#pragma unroll
            for (int n = 0; n < 4; ++n)
                acc[m][n] = __builtin_amdgcn_mfma_f32_16x16x32_bf16(aF[m], bF[n], acc[m][n], 0, 0, 0);
        __syncthreads();
        cur ^= 1;
    }

    const float* x2 = nrm + batch * L_DIM;
    const float* y2 = nrm + B_DIM * L_DIM + batch * L_DIM;
    float* outb = out + (size_t)batch * L_DIM * L_DIM;
    const int rbase = row0 + (wr << 6) + ((l >> 4) << 2);
    const int cbase = col0 + (wc << 6) + lr;
#pragma unroll
    for (int n = 0; n < 4; ++n) {
        const int col = cbase + (n << 4);
        const float y2v = y2[col];
#pragma unroll
        for (int m = 0; m < 4; ++m) {
            const int rowf = rbase + (m << 4);
#pragma unroll
            for (int r = 0; r < 4; ++r) {
                const int row = rowf + r;
                float sq = x2[row] + y2v - 2.0f * acc[m][n][r];
                sq = fmaxf(sq, 0.0f);
                outb[(size_t)row * L_DIM + col] = 1.0f / (1.0f + sqrtf(sq));
            }
        }
    }
}

extern "C" void kernel_launch(void* const* d_in, const int* in_sizes, int n_in,
                              void* d_out, int out_size, void* d_ws, size_t ws_size,
                              hipStream_t stream) {
    (void)in_sizes; (void)n_in; (void)out_size;
    const float* s1 = (const float*)d_in[1];
    const float* s2 = (const float*)d_in[2];
    float* out = (float*)d_out;

    const size_t NRM_BYTES = 2u * B_DIM * L_DIM * sizeof(float);          // 128 KB
    const size_t BF_BYTES = (size_t)B_DIM * L_DIM * D_DIM * sizeof(__hip_bfloat16);  // 8 MB each
    const size_t NEED = NRM_BYTES + 2 * BF_BYTES;                          // ~16.9 MB

    float* nrm = (float*)d_ws;
    if (ws_size >= NEED) {
        __hip_bfloat16* s1b = (__hip_bfloat16*)((char*)d_ws + NRM_BYTES);
        __hip_bfloat16* s2b = (__hip_bfloat16*)((char*)d_ws + NRM_BYTES + BF_BYTES);
        prep_kernel<<<2048, 256, 0, stream>>>(s1, s2, nrm, s1b, s2b);
        dist_gemm2_kernel<<<512, 256, 0, stream>>>(s1b, s2b, nrm, out);
    } else {
        norms_kernel<<<8192, 256, 0, stream>>>(s1, s2, nrm);
        dist_gemm_kernel<<<1024, 256, 0, stream>>>(s1, s2, nrm, out);
    }
}